// Round 1
// 333.072 us; speedup vs baseline: 1.1953x; 1.1953x over previous
//
#include <hip/hip_runtime.h>
#include <stdint.h>

typedef __attribute__((ext_vector_type(4))) int   v4i;
typedef __attribute__((ext_vector_type(8))) int   v8i;
typedef __attribute__((ext_vector_type(4))) float v4f;

#define BATCH 8192
#define KDIM  4096
#define NOUT  4096
#define KB    (KDIM / 2)   // bytes per packed fp4 row = 2048

// pack x: fp32 -> fp4 e2m1 {x>0 -> 1.0 (0x2), else 0.0 (0x0)}, 8 elems/thread
__global__ __launch_bounds__(256) void pack_x4(const float* __restrict__ x,
                                               uint32_t* __restrict__ xb) {
    int t = blockIdx.x * 256 + threadIdx.x;
    const float4* p = (const float4*)x + (size_t)t * 2;
    float4 f0 = p[0];
    float4 f1 = p[1];
    uint32_t b = (f0.x > 0.f ? 0x2u        : 0u)
               | (f0.y > 0.f ? 0x20u       : 0u)
               | (f0.z > 0.f ? 0x200u      : 0u)
               | (f0.w > 0.f ? 0x2000u     : 0u)
               | (f1.x > 0.f ? 0x20000u    : 0u)
               | (f1.y > 0.f ? 0x200000u   : 0u)
               | (f1.z > 0.f ? 0x2000000u  : 0u)
               | (f1.w > 0.f ? 0x20000000u : 0u);
    xb[t] = b;
}

// pack W: fp32 -> fp4 e2m1 {W>0 -> +1.0 (0x2), else -1.0 (0xA)}, 8 elems/thread
__global__ __launch_bounds__(256) void pack_w4(const float* __restrict__ w,
                                               uint32_t* __restrict__ wb) {
    int t = blockIdx.x * 256 + threadIdx.x;
    const float4* p = (const float4*)w + (size_t)t * 2;
    float4 f0 = p[0];
    float4 f1 = p[1];
    uint32_t b = (f0.x > 0.f ? 0x2u        : 0xAu)
               | (f0.y > 0.f ? 0x20u       : 0xA0u)
               | (f0.z > 0.f ? 0x200u      : 0xA00u)
               | (f0.w > 0.f ? 0x2000u     : 0xA000u)
               | (f1.x > 0.f ? 0x20000u    : 0xA0000u)
               | (f1.y > 0.f ? 0x200000u   : 0xA00000u)
               | (f1.z > 0.f ? 0x2000000u  : 0xA000000u)
               | (f1.w > 0.f ? 0x20000000u : 0xA0000000u);
    wb[t] = b;
}

// C[M,N] = A[M,K] * B[N,K]^T, fp4 e2m1 inputs (values in {0,1} x {-1,+1}),
// f32 out via MX-scaled MFMA with unit scales -> integer-exact.
// m97 structure unchanged: 128x128 block tile, 4 waves (2x2 of 64x64),
// global_load_lds width-16 staging with XOR chunk swizzle via the GLOBAL
// fetch address. K-tile = 128 fp4 elems = 64 B/row (identical byte layout
// to the old i8 BK=64 tile), 16x16x128 f8f6f4 MFMA, 4x4 acc tiles/wave.
__global__ __launch_bounds__(256) void bin_gemm4(const uint8_t* __restrict__ A,
                                                 const uint8_t* __restrict__ B,
                                                 float* __restrict__ C) {
    __shared__ __align__(16) uint8_t smA[128 * 64];
    __shared__ __align__(16) uint8_t smB[128 * 64];

    const int tid  = threadIdx.x;
    const int w    = tid >> 6;          // wave 0..3
    const int lane = tid & 63;
    const int q    = lane >> 4;         // quad 0..3 -> k-slice q*32..+32
    const int mp   = lane & 15;

    const int Mbase = blockIdx.y * 128;
    const int Nbase = blockIdx.x * 128;
    const int wm = (w >> 1) * 64;       // wave M offset in tile
    const int wn = (w & 1) * 64;        // wave N offset in tile

    const int srow = lane >> 2;
    const int swz  = ((lane & 3) ^ ((lane >> 3) & 3)) * 16;
    const int g0   = (w * 2 + 0) * 16;
    const int g1   = (w * 2 + 1) * 16;

    const uint8_t* gA0 = A + (size_t)(Mbase + g0 + srow) * KB + swz;
    const uint8_t* gA1 = A + (size_t)(Mbase + g1 + srow) * KB + swz;
    const uint8_t* gB0 = B + (size_t)(Nbase + g0 + srow) * KB + swz;
    const uint8_t* gB1 = B + (size_t)(Nbase + g1 + srow) * KB + swz;

    auto lA0 = (__attribute__((address_space(3))) void*)(smA + g0 * 64);
    auto lA1 = (__attribute__((address_space(3))) void*)(smA + g1 * 64);
    auto lB0 = (__attribute__((address_space(3))) void*)(smB + g0 * 64);
    auto lB1 = (__attribute__((address_space(3))) void*)(smB + g1 * 64);

    // Fragment read: A[m=mp][k-slice q] lives at row*64 + swizzled slot.
    const int slot = (q ^ ((mp >> 1) & 3)) * 16;

    v4f acc[4][4] = {};

    for (int kt = 0; kt < KDIM / 128; ++kt) {
        const int kof = kt * 64;        // 64 bytes = 128 fp4 elems per K-step
        __builtin_amdgcn_global_load_lds(
            (__attribute__((address_space(1))) void*)(gA0 + kof), lA0, 16, 0, 0);
        __builtin_amdgcn_global_load_lds(
            (__attribute__((address_space(1))) void*)(gA1 + kof), lA1, 16, 0, 0);
        __builtin_amdgcn_global_load_lds(
            (__attribute__((address_space(1))) void*)(gB0 + kof), lB0, 16, 0, 0);
        __builtin_amdgcn_global_load_lds(
            (__attribute__((address_space(1))) void*)(gB1 + kof), lB1, 16, 0, 0);
        __syncthreads();   // compiler emits vmcnt(0) drain before s_barrier

        v4i af[4], bf[4];
        #pragma unroll
        for (int i = 0; i < 4; ++i)
            af[i] = *(const v4i*)(smA + (wm + i * 16 + mp) * 64 + slot);
        #pragma unroll
        for (int i = 0; i < 4; ++i)
            bf[i] = *(const v4i*)(smB + (wn + i * 16 + mp) * 64 + slot);

        // fp4 operands occupy the low 4 regs of the 8-reg field; fmt 4 = e2m1.
        // Unit scale: E8M0 0x7F in every byte (opsel-proof).
        #pragma unroll
        for (int mi = 0; mi < 4; ++mi) {
            v8i a8 = {af[mi][0], af[mi][1], af[mi][2], af[mi][3], 0, 0, 0, 0};
            #pragma unroll
            for (int ni = 0; ni < 4; ++ni) {
                v8i b8 = {bf[ni][0], bf[ni][1], bf[ni][2], bf[ni][3], 0, 0, 0, 0};
                acc[mi][ni] = __builtin_amdgcn_mfma_scale_f32_16x16x128_f8f6f4(
                    a8, b8, acc[mi][ni], 4, 4,
                    0, 0x7F7F7F7F, 0, 0x7F7F7F7F);
            }
        }
        __syncthreads();   // all waves done reading before next overwrite
    }

    // C/D layout (shape-determined, dtype-independent): col = lane&15,
    // row = quad*4 + reg.
    float* Cp = C + (size_t)(Mbase + wm + q * 4) * NOUT + (Nbase + wn + mp);
    #pragma unroll
    for (int mi = 0; mi < 4; ++mi)
        #pragma unroll
        for (int ni = 0; ni < 4; ++ni)
            #pragma unroll
            for (int r = 0; r < 4; ++r)
                Cp[(size_t)(mi * 16 + r) * NOUT + ni * 16] = acc[mi][ni][r];
}

extern "C" void kernel_launch(void* const* d_in, const int* in_sizes, int n_in,
                              void* d_out, int out_size, void* d_ws, size_t ws_size,
                              hipStream_t stream) {
    const float* x = (const float*)d_in[0];   // [8192, 4096] f32
    const float* W = (const float*)d_in[1];   // [4096, 4096] f32, values +/-1
    float* out = (float*)d_out;               // [8192, 4096] f32

    uint8_t* xb = (uint8_t*)d_ws;                              // 16 MiB
    uint8_t* wb = (uint8_t*)d_ws + (size_t)BATCH * KDIM / 2;   // 8 MiB (24 MiB ws)

    pack_x4<<<(BATCH * (size_t)KDIM / 8) / 256, 256, 0, stream>>>(x, (uint32_t*)xb);
    pack_w4<<<((size_t)NOUT * KDIM / 8) / 256, 256, 0, stream>>>(W, (uint32_t*)wb);

    dim3 grid(NOUT / 128, BATCH / 128);   // (32, 64) = 2048 blocks
    bin_gemm4<<<grid, 256, 0, stream>>>(xb, wb, out);
}

// Round 3
// 322.657 us; speedup vs baseline: 1.2339x; 1.0323x over previous
//
#include <hip/hip_runtime.h>
#include <stdint.h>

typedef __attribute__((ext_vector_type(4))) int   v4i;
typedef __attribute__((ext_vector_type(8))) int   v8i;
typedef __attribute__((ext_vector_type(4))) float v4f;

#define BATCH 8192
#define KDIM  4096
#define NOUT  4096
#define KB    (KDIM / 2)     // bytes per packed fp4 row = 2048
#define BK_B  128            // K-tile bytes per row = 256 fp4 elems
#define NT    (KDIM / 256)   // 16 K-tiles

// pack x: fp32 -> fp4 e2m1 {x>0 -> 1.0 (0x2), else 0.0 (0x0)}, 8 elems/thread
__global__ __launch_bounds__(256) void pack_x4(const float* __restrict__ x,
                                               uint32_t* __restrict__ xb) {
    int t = blockIdx.x * 256 + threadIdx.x;
    const float4* p = (const float4*)x + (size_t)t * 2;
    float4 f0 = p[0];
    float4 f1 = p[1];
    uint32_t b = (f0.x > 0.f ? 0x2u        : 0u)
               | (f0.y > 0.f ? 0x20u       : 0u)
               | (f0.z > 0.f ? 0x200u      : 0u)
               | (f0.w > 0.f ? 0x2000u     : 0u)
               | (f1.x > 0.f ? 0x20000u    : 0u)
               | (f1.y > 0.f ? 0x200000u   : 0u)
               | (f1.z > 0.f ? 0x2000000u  : 0u)
               | (f1.w > 0.f ? 0x20000000u : 0u);
    xb[t] = b;
}

// pack W: fp32 -> fp4 e2m1 {W>0 -> +1.0 (0x2), else -1.0 (0xA)}, 8 elems/thread
__global__ __launch_bounds__(256) void pack_w4(const float* __restrict__ w,
                                               uint32_t* __restrict__ wb) {
    int t = blockIdx.x * 256 + threadIdx.x;
    const float4* p = (const float4*)w + (size_t)t * 2;
    float4 f0 = p[0];
    float4 f1 = p[1];
    uint32_t b = (f0.x > 0.f ? 0x2u        : 0xAu)
               | (f0.y > 0.f ? 0x20u       : 0xA0u)
               | (f0.z > 0.f ? 0x200u      : 0xA00u)
               | (f0.w > 0.f ? 0x2000u     : 0xA000u)
               | (f1.x > 0.f ? 0x20000u    : 0xA0000u)
               | (f1.y > 0.f ? 0x200000u   : 0xA00000u)
               | (f1.z > 0.f ? 0x2000000u  : 0xA000000u)
               | (f1.w > 0.f ? 0x20000000u : 0xA0000000u);
    wb[t] = b;
}

// C[M,N] = A[M,K] * B[N,K]^T, fp4 e2m1 (values {0,1} x {-1,+1}), f32 out —
// integer-exact via unit MX scales.
// 256x256 tile, 8 waves (2M x 4N), per-wave 128x64, BK = 256 fp4 = 128 B/row.
// T3 minimum 2-phase (catalog recipe, no inline asm): per K-tile,
//   STAGE(next tile) -> ds_read+MFMA(current) -> __syncthreads().
// The stage loads get the whole 64-MFMA compute phase (~2800 cyc) to land,
// so the syncthreads vmcnt(0) drain finds them complete. One barrier per
// 64 MFMAs (vs 2 per 16 in the m97 structure).
// LDS chunk XOR swizzle via pre-swizzled GLOBAL source (global_load_lds
// writes linearly): LDS row r slot s holds global chunk s ^ (r&7).
__global__ __launch_bounds__(512, 2) void bin_gemm4(const uint8_t* __restrict__ A,
                                                    const uint8_t* __restrict__ B,
                                                    float* __restrict__ C) {
    // [buf][A: 32 KiB | B: 32 KiB] x 2 = 128 KiB
    __shared__ __align__(16) uint8_t sm[131072];

    const int tid  = threadIdx.x;
    const int w    = tid >> 6;          // wave 0..7
    const int lane = tid & 63;
    const int q    = lane >> 4;         // quad -> 16B chunk within 64B k-slice
    const int mp   = lane & 15;

    const int Mbase = blockIdx.y * 256;
    const int Nbase = blockIdx.x * 256;
    const int wm = (w >> 2) * 128;      // wave M offset in tile
    const int wn = (w & 3) * 64;        // wave N offset in tile

    // Staging: one global_load_lds writes LDS base + lane*16 (1 KiB).
    // Lane covers row L*64 + w*8 + (lane>>3), slot lane&7; fetch global
    // chunk (lane&7) ^ ((lane>>3)&7)  (srow base rows are %8 == 0).
    const int srow = w * 8 + (lane >> 3);
    const int swz  = ((lane & 7) ^ ((lane >> 3) & 7)) * 16;

    const uint8_t* pA = A + (size_t)(Mbase + srow) * KB + swz;
    const uint8_t* pB = B + (size_t)(Nbase + srow) * KB + swz;
    const int ldsw = w * 1024;          // wave-uniform LDS chunk base

    // Read slot for chunk c of row r: c ^ (r&7); all frag rows have r&7 == mp&7.
    const int rsw = mp & 7;

    v4f acc[8][4] = {};

    // ---- prologue: stage tile 0 into buf 0, drain ----
    #pragma unroll
    for (int L = 0; L < 4; ++L) {
        __builtin_amdgcn_global_load_lds(
            (__attribute__((address_space(1))) void*)(pA + (size_t)(L * 64) * KB),
            (__attribute__((address_space(3))) void*)(sm + L * 8192 + ldsw), 16, 0, 0);
        __builtin_amdgcn_global_load_lds(
            (__attribute__((address_space(1))) void*)(pB + (size_t)(L * 64) * KB),
            (__attribute__((address_space(3))) void*)(sm + 32768 + L * 8192 + ldsw), 16, 0, 0);
    }
    __syncthreads();

    for (int t = 0; t < NT; ++t) {
        // ---- issue next tile's 8 loads FIRST (overlap with compute) ----
        if (t + 1 < NT) {
            const int nb  = (t + 1) & 1;
            const int kof = (t + 1) * BK_B;
            #pragma unroll
            for (int L = 0; L < 4; ++L) {
                __builtin_amdgcn_global_load_lds(
                    (__attribute__((address_space(1))) void*)(pA + (size_t)(L * 64) * KB + kof),
                    (__attribute__((address_space(3))) void*)(sm + nb * 65536 + L * 8192 + ldsw),
                    16, 0, 0);
                __builtin_amdgcn_global_load_lds(
                    (__attribute__((address_space(1))) void*)(pB + (size_t)(L * 64) * KB + kof),
                    (__attribute__((address_space(3))) void*)(sm + nb * 65536 + 32768 + L * 8192 + ldsw),
                    16, 0, 0);
            }
        }

        // ---- compute current tile: 24 ds_read_b128 + 64 MFMA ----
        const uint8_t* sA = sm + (t & 1) * 65536;
        const uint8_t* sB = sA + 32768;

        v4i bfr[4][2];
        #pragma unroll
        for (int ni = 0; ni < 4; ++ni)
            #pragma unroll
            for (int ks = 0; ks < 2; ++ks)
                bfr[ni][ks] = *(const v4i*)(sB + (wn + ni * 16 + mp) * 128
                                            + ((ks * 4 + q) ^ rsw) * 16);

        #pragma unroll
        for (int p = 0; p < 4; ++p) {
            v4i afr[2][2];
            #pragma unroll
            for (int i = 0; i < 2; ++i)
                #pragma unroll
                for (int ks = 0; ks < 2; ++ks)
                    afr[i][ks] = *(const v4i*)(sA + (wm + (p * 2 + i) * 16 + mp) * 128
                                               + ((ks * 4 + q) ^ rsw) * 16);
            #pragma unroll
            for (int i = 0; i < 2; ++i)
                #pragma unroll
                for (int ni = 0; ni < 4; ++ni)
                    #pragma unroll
                    for (int ks = 0; ks < 2; ++ks) {
                        v8i a8 = {afr[i][ks][0], afr[i][ks][1], afr[i][ks][2], afr[i][ks][3],
                                  0, 0, 0, 0};
                        v8i b8 = {bfr[ni][ks][0], bfr[ni][ks][1], bfr[ni][ks][2],
                                  bfr[ni][ks][3], 0, 0, 0, 0};
                        acc[p * 2 + i][ni] = __builtin_amdgcn_mfma_scale_f32_16x16x128_f8f6f4(
                            a8, b8, acc[p * 2 + i][ni], 4, 4,
                            0, 0x7F7F7F7F, 0, 0x7F7F7F7F);
                    }
        }

        // one barrier per K-tile: drains this iter's loads (already landed
        // under compute) + covers write-after-read for the buffer swap
        __syncthreads();
    }

    // C/D layout (shape-determined): col = lane&15, row = quad*4 + reg.
    float* Cp = C + (size_t)(Mbase + wm + q * 4) * NOUT + (Nbase + wn + mp);
    #pragma unroll
    for (int mi = 0; mi < 8; ++mi)
        #pragma unroll
        for (int ni = 0; ni < 4; ++ni)
            #pragma unroll
            for (int r = 0; r < 4; ++r)
                Cp[(size_t)(mi * 16 + r) * NOUT + ni * 16] = acc[mi][ni][r];
}

extern "C" void kernel_launch(void* const* d_in, const int* in_sizes, int n_in,
                              void* d_out, int out_size, void* d_ws, size_t ws_size,
                              hipStream_t stream) {
    const float* x = (const float*)d_in[0];   // [8192, 4096] f32
    const float* W = (const float*)d_in[1];   // [4096, 4096] f32, values +/-1
    float* out = (float*)d_out;               // [8192, 4096] f32

    uint8_t* xb = (uint8_t*)d_ws;                              // 16 MiB
    uint8_t* wb = (uint8_t*)d_ws + (size_t)BATCH * KDIM / 2;   // 8 MiB (24 MiB ws)

    pack_x4<<<(BATCH * (size_t)KDIM / 8) / 256, 256, 0, stream>>>(x, (uint32_t*)xb);
    pack_w4<<<((size_t)NOUT * KDIM / 8) / 256, 256, 0, stream>>>(W, (uint32_t*)wb);

    dim3 grid(NOUT / 256, BATCH / 256);   // (16, 32) = 512 blocks
    bin_gemm4<<<grid, 512, 0, stream>>>(xb, wb, out);
}